// Round 1
// baseline (23.730 us; speedup 1.0000x reference)
//
#include <hip/hip_runtime.h>

#define B_    32
#define T_    256
#define D_    64
#define NSEG_ 32
#define OUTD_ (D_ + (D_*(D_-1))/2)   // 64 + 2016 = 2080

// starts[k] = int(round(1 + k*255/32)) - 1, Python banker's rounding.
// Exact in double; rint() is round-nearest-even -> bit-identical to numpy/python.
__device__ __forceinline__ int boundary(int k) {
    double v = 1.0 + (double)k * (255.0 / 32.0);
    return (int)rint(v) - 1;
}

__global__ __launch_bounds__(256)
void logsig_kernel(const float* __restrict__ inp, float* __restrict__ out) {
    const int s = blockIdx.x;   // segment
    const int b = blockIdx.y;   // batch
    const int t0 = boundary(s);
    const int t1 = boundary(s + 1);
    const int n  = t1 - t0;     // dx steps in this segment (7 or 8)
    const int npts = n + 1;     // points used (<= 9)

    __shared__ float xs[9][D_];
    const float* src = inp + ((size_t)b * T_ + t0) * D_;
    for (int i = threadIdx.x; i < npts * D_; i += blockDim.x) {
        xs[i / D_][i % D_] = src[i];
    }
    __syncthreads();

    float* o = out + ((size_t)b * NSEG_ + s) * OUTD_;
    for (int j = threadIdx.x; j < OUTD_; j += blockDim.x) {
        if (j < D_) {
            // s1 = xb - xa
            o[j] = xs[n][j] - xs[0][j];
        } else {
            // linear upper-tri index -> (d, e), row-major, k=1 diag offset
            int rem = j - D_;
            int d = 0;
            while (rem >= (D_ - 1 - d)) { rem -= (D_ - 1 - d); ++d; }
            const int e = d + 1 + rem;

            // A[d,e] = 0.5*( sum_t (x_t[d] x_{t+1}[e] - x_t[e] x_{t+1}[d])
            //               - (x_{t0}[d] x_{t1}[e] - x_{t0}[e] x_{t1}[d]) )
            float acc = 0.0f;
            #pragma unroll
            for (int t = 0; t < 8; ++t) {
                if (t < n) {
                    acc += xs[t][d] * xs[t + 1][e] - xs[t][e] * xs[t + 1][d];
                }
            }
            acc -= xs[0][d] * xs[n][e] - xs[0][e] * xs[n][d];
            o[j] = 0.5f * acc;
        }
    }
}

extern "C" void kernel_launch(void* const* d_in, const int* in_sizes, int n_in,
                              void* d_out, int out_size, void* d_ws, size_t ws_size,
                              hipStream_t stream) {
    const float* inp = (const float*)d_in[0];
    float* out = (float*)d_out;
    dim3 grid(NSEG_, B_);
    dim3 block(256);
    hipLaunchKernelGGL(logsig_kernel, grid, block, 0, stream, inp, out);
}

// Round 2
// 18.201 us; speedup vs baseline: 1.3038x; 1.3038x over previous
//
#include <hip/hip_runtime.h>

#define B_    32
#define T_    256
#define D_    64
#define NSEG_ 32
#define OUTD_ (D_ + (D_*(D_-1))/2)   // 64 + 2016 = 2080

// starts[k] = int(round(1 + k*255/32)) - 1, Python banker's rounding.
// Exact in double; rint() is round-nearest-even -> bit-identical to numpy.
__device__ __forceinline__ int boundary(int k) {
    double v = 1.0 + (double)k * (255.0 / 32.0);
    return (int)rint(v) - 1;
}

// Cumulative upper-tri (k=1) elements before row d:  C(d) = d*(127-d)/2  (exact int)
__device__ __forceinline__ int cum(int d) { return (d * (127 - d)) >> 1; }

// Invert rem -> (d, e): closed form via float sqrt, then +-1 integer correction.
__device__ __forceinline__ void decode(int rem, int& d, int& e) {
    float disc = 16129.0f - 8.0f * (float)rem;   // 127^2 - 8*rem, >= 9
    int dd = (int)((127.0f - sqrtf(disc)) * 0.5f);
    dd = max(0, min(62, dd));
    while (dd > 0 && cum(dd) > rem) --dd;        // <=1 iter in practice
    while (cum(dd + 1) <= rem) ++dd;             // <=1 iter in practice
    d = dd;
    e = dd + 1 + (rem - cum(dd));
}

__global__ __launch_bounds__(256)
void logsig_kernel(const float* __restrict__ inp, float* __restrict__ out) {
    const int s = blockIdx.x;   // segment
    const int b = blockIdx.y;   // batch
    const int t0 = boundary(s);
    const int t1 = boundary(s + 1);
    const int n  = t1 - t0;     // steps in this segment (7 or 8)
    const int npts = n + 1;     // points (<= 9)

    __shared__ float xs[9][D_];
    const float* src = inp + ((size_t)b * T_ + t0) * D_;
    for (int i = threadIdx.x; i < npts * D_; i += blockDim.x) {
        xs[i / D_][i % D_] = src[i];
    }
    __syncthreads();

    float* o = out + ((size_t)b * NSEG_ + s) * OUTD_;
    for (int j = threadIdx.x; j < OUTD_; j += blockDim.x) {
        if (j < D_) {
            o[j] = xs[n][j] - xs[0][j];          // s1 = xb - xa
        } else {
            int d, e;
            decode(j - D_, d, e);
            // A[d,e] = 0.5*( sum_t (x_t[d] x_{t+1}[e] - x_t[e] x_{t+1}[d])
            //               - (x_{t0}[d] x_{t1}[e] - x_{t0}[e] x_{t1}[d]) )
            float acc = 0.0f;
            #pragma unroll
            for (int t = 0; t < 8; ++t) {
                if (t < n) {
                    acc = fmaf(xs[t][d],  xs[t + 1][e], acc);
                    acc = fmaf(xs[t][e], -xs[t + 1][d], acc);
                }
            }
            acc = fmaf(xs[0][d], -xs[n][e], acc);
            acc = fmaf(xs[0][e],  xs[n][d], acc);
            o[j] = 0.5f * acc;
        }
    }
}

extern "C" void kernel_launch(void* const* d_in, const int* in_sizes, int n_in,
                              void* d_out, int out_size, void* d_ws, size_t ws_size,
                              hipStream_t stream) {
    const float* inp = (const float*)d_in[0];
    float* out = (float*)d_out;
    dim3 grid(NSEG_, B_);
    dim3 block(256);
    hipLaunchKernelGGL(logsig_kernel, grid, block, 0, stream, inp, out);
}